// Round 6
// baseline (226.655 us; speedup 1.0000x reference)
//
#include <hip/hip_runtime.h>
#include <hip/hip_cooperative_groups.h>

#define WIDTH 1024
#define HEIGHT 1024
#define IMG_ELEMS (WIDTH * HEIGHT)
#define TPX 32                 // tiles per axis (32x32-pixel tiles)
#define NTILES (TPX * TPX)     // 1024
#define NB 256                 // blocks (pass 1 / fused grid)
#define BT 1024                // threads per block
#define BSTRIDE 8192           // payload entries per block region (ppb <= 8192)
#define CAPP 36                // max points per pixel bucket      (lambda=7.63)
#define PTS_CAP 8448           // max points per tile              (lambda=7812)

// Shared-memory carve (u32 units), 37376 u32 = 149504 B, 1 block/CU.
// Pass 2: pts region reused as T01/T11 exchange planes after the reduce.
#define OFF_PTS   0
#define OFF_BIDX  (OFF_PTS + 2 * PTS_CAP)            // uint16[NTILES*CAPP]
#define OFF_HCNT  (OFF_BIDX + (NTILES * CAPP) / 2)
#define OFF_RCNT  (OFF_HCNT + NTILES)
#define OFF_RDST  (OFF_RCNT + NB)
#define OFF_ROFF  (OFF_RDST + NB)
#define OFF_STMP  (OFF_ROFF + NB)
#define SMEM_U32  (OFF_STMP + NB)
// Pass 1 aliases (disjoint lifetime, separated by grid.sync + barriers):
//   stage  = smem[0 .. 16384)   (uint2[8192], 64 KB dense staging)
//   cursor = smem[16384 .. 17408)
//   wtot   = smem[17408 .. 17424)

// sigma=0.1 -> 2x2 separable splat (taps beyond the bracketing pair < 2e-22).
// ax = wx0/(wx0+wx1) = 1/(1+exp(100*xf-50)).
// Measured HW model: global fp32 atomic = 32B memory-side txn (~20 G/s);
// LDS atomics ~2.9 cyc/lane on the PER-CU pipe (R15's 4-atomics/pt design
// = 38 us floor -> 52 us measured regression; 1 atomic/pt/pass = ~9.4 us/pass
// floor = the kernel-side wall); harness poison/restore ~65-70 us fixed
// floor (256 MiB ws poison fill at 5.8-6.5 TB/s, independent of our usage);
// ~2 us per graph launch.
// R17: fuse pass1+pass2 into ONE cooperative kernel (grid 256, 1 block/CU
// guaranteed by the 149.5 KB LDS carve): saves one launch + inter-kernel
// drain, and replaces 768 empty k_accum block dispatches with in-kernel
// skips. Inner loops byte-identical to R16 (94.5 us). Fallback to the
// two-kernel R16 path if cooperative launch is unsupported.

__device__ __forceinline__ void point_geom(float px, float py, int& cxb, int& cyb,
                                           float& ax, float& ay) {
    // (p - X0)/DX == (p + 1) * 512 exactly (DX = 2^-9).
    float xp = (px + 1.0f) * 512.0f;
    float yp = (py + 1.0f) * 512.0f;
    int xb = (int)floorf(xp);
    int yb = (int)floorf(yp);
    float xf = xp - (float)xb;
    float yf = yp - (float)yb;
    // wx1/wx0 = exp(100*xf - 50)  ->  ax = 1/(1 + exp(100*xf - 50)).
    ax = 1.0f / (1.0f + __expf(100.0f * xf - 50.0f));
    ay = 1.0f / (1.0f + __expf(100.0f * yf - 50.0f));
    cxb = min(max(xb, 0), WIDTH - 1);
    cyb = min(max(yb, 0), HEIGHT - 1);
}

// ---------------- fused cooperative kernel ----------------
__global__ void __launch_bounds__(BT)
k_fused(const float* __restrict__ x, const float* __restrict__ y,
        const float* __restrict__ v, uint2* __restrict__ payload,
        unsigned* __restrict__ runCnt, float* __restrict__ out,
        int n, int ppb) {
    __shared__ __align__(16) unsigned smem[SMEM_U32];
    int b = blockIdx.x;
    int p = threadIdx.x;
    unsigned lane = p & 63, w = p >> 6;

    // ================= pass 1: zero + count + sort + pack =================
    {
        uint2*    stage  = (uint2*)&smem[0];
        unsigned* cursor = &smem[16384];
        unsigned* wtot   = &smem[17408];

        cursor[p] = 0u;
        ((float4*)out)[(unsigned)b * 1024u + p] = make_float4(0.f, 0.f, 0.f, 0.f);
        __syncthreads();

        int lo = b * ppb;                   // ppb % 8 == 0 -> 16B-aligned base
        int hi = min(n, lo + ppb);

        uint2 pay[8];
        unsigned meta[8];                   // tile<<16 | pos ; ~0u = invalid

        auto enc = [&](int s, float px, float py, float pv) {
            int cxb, cyb; float ax, ay;
            point_geom(px, py, cxb, cyb, ax, ay);
            unsigned tile = (unsigned)((cyb >> 5) * TPX + (cxb >> 5));
            unsigned pos = atomicAdd(&cursor[tile], 1u);   // pos < ppb <= 8192
            unsigned axq = (unsigned)(ax * 2047.0f + 0.5f);
            unsigned ayq = (unsigned)(ay * 2047.0f + 0.5f);
            pay[s] = make_uint2(__float_as_uint(pv),
                                axq | (ayq << 11) | ((unsigned)(cxb & 31) << 22) |
                                ((unsigned)(cyb & 31) << 27));
            meta[s] = (tile << 16) | pos;
        };

#pragma unroll
        for (int it = 0; it < 2; ++it) {    // BT*4*2 = 8192 >= ppb
            int base = lo + p * 4 + it * (BT * 4);
            if (base + 3 < hi) {
                float4 x4 = *(const float4*)&x[base];
                float4 y4 = *(const float4*)&y[base];
                float4 v4 = *(const float4*)&v[base];
                enc(it * 4 + 0, x4.x, y4.x, v4.x);
                enc(it * 4 + 1, x4.y, y4.y, v4.y);
                enc(it * 4 + 2, x4.z, y4.z, v4.z);
                enc(it * 4 + 3, x4.w, y4.w, v4.w);
            } else {
#pragma unroll
                for (int j = 0; j < 4; ++j) {
                    int idx = base + j;
                    if (idx < hi) enc(it * 4 + j, x[idx], y[idx], v[idx]);
                    else          meta[it * 4 + j] = 0xFFFFFFFFu;
                }
            }
        }
        __syncthreads();

        // Exclusive scan of the 1024 tile counts (shuffle + 16 wave partials).
        unsigned c = cursor[p];
        unsigned vsc = c;
#pragma unroll
        for (int d = 1; d < 64; d <<= 1) {
            unsigned t_ = __shfl_up(vsc, d, 64);
            if (lane >= (unsigned)d) vsc += t_;
        }
        if (lane == 63) wtot[w] = vsc;
        __syncthreads();
        if (p == 0) {
            unsigned a = 0;
#pragma unroll
            for (int k = 0; k < BT / 64; ++k) { unsigned t_ = wtot[k]; wtot[k] = a; a += t_; }
        }
        __syncthreads();
        unsigned excl = vsc - c + wtot[w];
        runCnt[(unsigned)p * NB + (unsigned)b] = (excl << 16) | c;   // [t][b]
        cursor[p] = excl;
        __syncthreads();

        // Scatter into dense LDS staging (random 8B LDS writes).
#pragma unroll
        for (int s = 0; s < 8; ++s) {
            unsigned m = meta[s];
            if (m != 0xFFFFFFFFu)
                stage[cursor[m >> 16] + (m & 0xFFFFu)] = pay[s];
        }
        __syncthreads();

        // Stream out coalesced: payload[b*8192 .. b*8192+ppb).
        int nv = ppb >> 1;
        uint4* dstv = (uint4*)(payload + ((size_t)b << 13));
        const uint4* srcv = (const uint4*)stage;
        for (int i = p; i < nv; i += BT) dstv[i] = srcv[i];
    }

    __threadfence();
    cooperative_groups::this_grid().sync();

    // ================= pass 2: 4 tiles per block, heavy first =================
    uint2*          pts  = (uint2*)&smem[OFF_PTS];
    unsigned short* bidx = (unsigned short*)&smem[OFF_BIDX];
    unsigned*       hcnt = &smem[OFF_HCNT];
    unsigned*       rcnt = &smem[OFF_RCNT];
    unsigned*       rdst = &smem[OFF_RDST];
    unsigned*       roff = &smem[OFF_ROFF];
    unsigned*       stmp = &smem[OFF_STMP];
    float*          exT01 = (float*)&smem[OFF_PTS];
    float*          exT11 = (float*)&smem[OFF_PTS + BT];

    for (int sub = 0; sub < 4; ++sub) {
        unsigned bb = (unsigned)b + ((unsigned)sub << 8);
        // Static swizzle: virtual blocks 0..255 -> heavy tiles [16,31]^2.
        unsigned t;
        if (bb < 256u) {
            t = (16u + (bb >> 4)) * 32u + 16u + (bb & 15u);
        } else {
            unsigned r = bb - 256u;
            if (r < 512u) t = r;
            else { unsigned q = r - 512u; t = (16u + (q >> 4)) * 32u + (q & 15u); }
        }

        unsigned c0 = 0u;
        if (p < NB) {
            unsigned pk = runCnt[t * NB + (unsigned)p];   // coalesced
            c0 = pk & 0xFFFFu;
            rcnt[p] = c0;
            roff[p] = pk >> 16;
        }
        hcnt[p] = 0u;
        unsigned tsum = c0;
#pragma unroll
        for (int d = 32; d >= 1; d >>= 1) tsum += __shfl_down(tsum, d, 64);
        if (p < NB && lane == 0) rdst[w] = tsum;
        __syncthreads();
        unsigned total = rdst[0] + rdst[1] + rdst[2] + rdst[3];
        if (total == 0) { __syncthreads(); continue; }   // uniform

        // Exclusive scan of the 256 run counts.
        unsigned vsc = c0;
#pragma unroll
        for (int d = 1; d < 64; d <<= 1) {
            unsigned tmp = __shfl_up(vsc, d, 64);
            if (lane >= (unsigned)d) vsc += tmp;
        }
        __syncthreads();
        if (p < NB && lane == 63) stmp[w] = vsc;
        __syncthreads();
        if (p == 0) {
            unsigned a = 0;
#pragma unroll
            for (int k = 0; k < 4; ++k) { unsigned tt = stmp[k]; stmp[k] = a; a += tt; }
        }
        __syncthreads();
        if (p < NB) rdst[p] = vsc - c0 + stmp[w];
        __syncthreads();

        // Gather + bucket: wave w handles runs [w*16, w*16+16), 8 in parallel.
        unsigned subr = lane >> 3, jl = lane & 7u;
#pragma unroll
        for (int kk = 0; kk < 2; ++kk) {
            int r = (int)w * 16 + kk * 8 + (int)subr;
            unsigned cnt = rcnt[r], dst = rdst[r];
            const uint2* g = payload + (((size_t)r) << 13) + roff[r];
            for (unsigned j = jl; j < cnt; j += 8) {
                uint2 pl = g[j];
                unsigned slot = dst + j;
                if (slot < PTS_CAP) {
                    pts[slot] = pl;
                    unsigned pix = (pl.y >> 22) & 1023u;
                    unsigned pos = atomicAdd(&hcnt[pix], 1u);
                    if (pos < CAPP) bidx[pix * CAPP + pos] = (unsigned short)slot;
                }
            }
        }
        __syncthreads();

        // Per-pixel register reduction (conflict-free ownership).
        float t00 = 0.0f, t10 = 0.0f, t01 = 0.0f, t11 = 0.0f;
        unsigned cnt = min(hcnt[p], (unsigned)CAPP);
        for (unsigned e = 0; e < cnt; ++e) {
            uint2 sp = pts[bidx[p * CAPP + e]];
            float val = __uint_as_float(sp.x);
            float ax = (float)(sp.y & 2047u) * (1.0f / 2047.0f);
            float ay = (float)((sp.y >> 11) & 2047u) * (1.0f / 2047.0f);
            float bx = 1.0f - ax, by = 1.0f - ay;
            t00 += val * ax * ay;
            t10 += val * bx * ay;
            t01 += val * ax * by;
            t11 += val * bx * by;
        }
        __syncthreads();             // pts/bidx dead; reuse as exchange planes
        exT01[p] = t01;
        exT11[p] = t11;
        __syncthreads();

        int lx = p & 31, ly = p >> 5;
        int gx = (int)((t & 31u) << 5) + lx;
        int gy = (int)((t >> 5) << 5) + ly;
        size_t g = (size_t)gy * WIDTH + gx;
        float t10l = __shfl_up(t10, 1, 64);   // T10 of (ly, lx-1): same wave
        float sum = t00;
        if (lx > 0) sum += t10l;
        if (ly > 0) sum += exT01[p - 32];
        if (lx > 0 && ly > 0) sum += exT11[p - 33];
        if (lx == 0 || ly == 0) atomicAdd(&out[g], sum);  // may race with halo
        else out[g] = sum;                                 // interior: exclusive

        // Cross-tile halo exports (targets always written atomically).
        bool xr = (gx + 1 < WIDTH), yd = (gy + 1 < HEIGHT);
        if (lx == 31 && xr) {
            atomicAdd(&out[g + 1], t10);
            if (yd) atomicAdd(&out[g + WIDTH + 1], t11);
        }
        if (ly == 31 && yd) {
            atomicAdd(&out[g + WIDTH], t01);
            if (lx < 31 && xr) atomicAdd(&out[g + WIDTH + 1], t11);
        }
    }
}

// ---------------- R16 two-kernel fallback (proven, 94.5 us) ----------------
__global__ void __launch_bounds__(BT)
k_sortlocal(const float* __restrict__ x, const float* __restrict__ y,
            const float* __restrict__ v, uint2* __restrict__ payload,
            unsigned* __restrict__ runCnt, float4* __restrict__ outv,
            int n, int ppb) {
    __shared__ unsigned cursor[NTILES];
    __shared__ unsigned wtot[BT / 64];
    __shared__ __align__(16) uint2 stage[BSTRIDE];

    int b = blockIdx.x;
    int p = threadIdx.x;
    cursor[p] = 0u;
    outv[(unsigned)b * 1024u + p] = make_float4(0.f, 0.f, 0.f, 0.f);
    __syncthreads();

    int lo = b * ppb;
    int hi = min(n, lo + ppb);
    uint2 pay[8];
    unsigned meta[8];

    auto enc = [&](int s, float px, float py, float pv) {
        int cxb, cyb; float ax, ay;
        point_geom(px, py, cxb, cyb, ax, ay);
        unsigned tile = (unsigned)((cyb >> 5) * TPX + (cxb >> 5));
        unsigned pos = atomicAdd(&cursor[tile], 1u);
        unsigned axq = (unsigned)(ax * 2047.0f + 0.5f);
        unsigned ayq = (unsigned)(ay * 2047.0f + 0.5f);
        pay[s] = make_uint2(__float_as_uint(pv),
                            axq | (ayq << 11) | ((unsigned)(cxb & 31) << 22) |
                            ((unsigned)(cyb & 31) << 27));
        meta[s] = (tile << 16) | pos;
    };

#pragma unroll
    for (int it = 0; it < 2; ++it) {
        int base = lo + p * 4 + it * (BT * 4);
        if (base + 3 < hi) {
            float4 x4 = *(const float4*)&x[base];
            float4 y4 = *(const float4*)&y[base];
            float4 v4 = *(const float4*)&v[base];
            enc(it * 4 + 0, x4.x, y4.x, v4.x);
            enc(it * 4 + 1, x4.y, y4.y, v4.y);
            enc(it * 4 + 2, x4.z, y4.z, v4.z);
            enc(it * 4 + 3, x4.w, y4.w, v4.w);
        } else {
#pragma unroll
            for (int j = 0; j < 4; ++j) {
                int idx = base + j;
                if (idx < hi) enc(it * 4 + j, x[idx], y[idx], v[idx]);
                else          meta[it * 4 + j] = 0xFFFFFFFFu;
            }
        }
    }
    __syncthreads();

    unsigned c = cursor[p];
    unsigned lane = p & 63, w = p >> 6;
    unsigned vsc = c;
#pragma unroll
    for (int d = 1; d < 64; d <<= 1) {
        unsigned t_ = __shfl_up(vsc, d, 64);
        if (lane >= (unsigned)d) vsc += t_;
    }
    if (lane == 63) wtot[w] = vsc;
    __syncthreads();
    if (p == 0) {
        unsigned a = 0;
#pragma unroll
        for (int k = 0; k < BT / 64; ++k) { unsigned t_ = wtot[k]; wtot[k] = a; a += t_; }
    }
    __syncthreads();
    unsigned excl = vsc - c + wtot[w];
    runCnt[(unsigned)p * NB + (unsigned)b] = (excl << 16) | c;
    cursor[p] = excl;
    __syncthreads();

#pragma unroll
    for (int s = 0; s < 8; ++s) {
        unsigned m = meta[s];
        if (m != 0xFFFFFFFFu)
            stage[cursor[m >> 16] + (m & 0xFFFFu)] = pay[s];
    }
    __syncthreads();

    int nv = ppb >> 1;
    uint4* dstv = (uint4*)(payload + ((size_t)b << 13));
    const uint4* srcv = (const uint4*)stage;
    for (int i = p; i < nv; i += BT) dstv[i] = srcv[i];
}

__global__ void __launch_bounds__(BT)
k_accum(const uint2* __restrict__ payload, const unsigned* __restrict__ runCnt,
        float* __restrict__ out) {
    __shared__ unsigned smem[SMEM_U32];
    uint2*          pts  = (uint2*)&smem[OFF_PTS];
    unsigned short* bidx = (unsigned short*)&smem[OFF_BIDX];
    unsigned*       hcnt = &smem[OFF_HCNT];
    unsigned*       rcnt = &smem[OFF_RCNT];
    unsigned*       rdst = &smem[OFF_RDST];
    unsigned*       roff = &smem[OFF_ROFF];
    unsigned*       stmp = &smem[OFF_STMP];
    float*          exT01 = (float*)&smem[OFF_PTS];
    float*          exT11 = (float*)&smem[OFF_PTS + BT];

    unsigned b = blockIdx.x;
    unsigned t;
    if (b < 256u) {
        t = (16u + (b >> 4)) * 32u + 16u + (b & 15u);
    } else {
        unsigned r = b - 256u;
        if (r < 512u) t = r;
        else { unsigned q = r - 512u; t = (16u + (q >> 4)) * 32u + (q & 15u); }
    }

    int p = threadIdx.x;
    unsigned lane = p & 63, w = p >> 6;
    unsigned c0 = 0u;
    if (p < NB) {
        unsigned pk = runCnt[t * NB + (unsigned)p];
        c0 = pk & 0xFFFFu;
        rcnt[p] = c0;
        roff[p] = pk >> 16;
    }
    hcnt[p] = 0u;
    unsigned tsum = c0;
#pragma unroll
    for (int d = 32; d >= 1; d >>= 1) tsum += __shfl_down(tsum, d, 64);
    if (p < NB && lane == 0) rdst[w] = tsum;
    __syncthreads();
    unsigned total = rdst[0] + rdst[1] + rdst[2] + rdst[3];
    if (total == 0) return;

    unsigned vsc = c0;
#pragma unroll
    for (int d = 1; d < 64; d <<= 1) {
        unsigned tmp = __shfl_up(vsc, d, 64);
        if (lane >= (unsigned)d) vsc += tmp;
    }
    __syncthreads();
    if (p < NB && lane == 63) stmp[w] = vsc;
    __syncthreads();
    if (p == 0) {
        unsigned a = 0;
#pragma unroll
        for (int k = 0; k < 4; ++k) { unsigned tt = stmp[k]; stmp[k] = a; a += tt; }
    }
    __syncthreads();
    if (p < NB) rdst[p] = vsc - c0 + stmp[w];
    __syncthreads();

    unsigned sub = lane >> 3, jl = lane & 7u;
#pragma unroll
    for (int kk = 0; kk < 2; ++kk) {
        int r = (int)w * 16 + kk * 8 + (int)sub;
        unsigned cnt = rcnt[r], dst = rdst[r];
        const unsigned long long* g =
            (const unsigned long long*)(payload + (((size_t)r) << 13) + roff[r]);
        for (unsigned j = jl; j < cnt; j += 8) {
            unsigned long long raw = __builtin_nontemporal_load(&g[j]);
            uint2 pl = make_uint2((unsigned)raw, (unsigned)(raw >> 32));
            unsigned slot = dst + j;
            if (slot < PTS_CAP) {
                pts[slot] = pl;
                unsigned pix = (pl.y >> 22) & 1023u;
                unsigned pos = atomicAdd(&hcnt[pix], 1u);
                if (pos < CAPP) bidx[pix * CAPP + pos] = (unsigned short)slot;
            }
        }
    }
    __syncthreads();

    float t00 = 0.0f, t10 = 0.0f, t01 = 0.0f, t11 = 0.0f;
    unsigned cnt = min(hcnt[p], (unsigned)CAPP);
    for (unsigned e = 0; e < cnt; ++e) {
        uint2 sp = pts[bidx[p * CAPP + e]];
        float val = __uint_as_float(sp.x);
        float ax = (float)(sp.y & 2047u) * (1.0f / 2047.0f);
        float ay = (float)((sp.y >> 11) & 2047u) * (1.0f / 2047.0f);
        float bx = 1.0f - ax, by = 1.0f - ay;
        t00 += val * ax * ay;
        t10 += val * bx * ay;
        t01 += val * ax * by;
        t11 += val * bx * by;
    }
    __syncthreads();
    exT01[p] = t01;
    exT11[p] = t11;
    __syncthreads();

    int lx = p & 31, ly = p >> 5;
    int gx = (int)((t & 31u) << 5) + lx;
    int gy = (int)((t >> 5) << 5) + ly;
    size_t g = (size_t)gy * WIDTH + gx;
    float t10l = __shfl_up(t10, 1, 64);
    float sum = t00;
    if (lx > 0) sum += t10l;
    if (ly > 0) sum += exT01[p - 32];
    if (lx > 0 && ly > 0) sum += exT11[p - 33];
    if (lx == 0 || ly == 0) atomicAdd(&out[g], sum);
    else out[g] = sum;

    bool xr = (gx + 1 < WIDTH), yd = (gy + 1 < HEIGHT);
    if (lx == 31 && xr) {
        atomicAdd(&out[g + 1], t10);
        if (yd) atomicAdd(&out[g + WIDTH + 1], t11);
    }
    if (ly == 31 && yd) {
        atomicAdd(&out[g + WIDTH], t01);
        if (lx < 31 && xr) atomicAdd(&out[g + WIDTH + 1], t11);
    }
}

// Fallback: direct memory-side atomics if workspace too small.
__global__ void __launch_bounds__(256)
splat_direct(const float* __restrict__ x, const float* __restrict__ y,
             const float* __restrict__ v, float* __restrict__ out, int n) {
    int i = blockIdx.x * blockDim.x + threadIdx.x;
    if (i >= n) return;
    int cxb, cyb; float ax, ay;
    point_geom(x[i], y[i], cxb, cyb, ax, ay);
    float val = v[i];
    float bx = 1.0f - ax, by = 1.0f - ay;
    float* row = out + cyb * WIDTH;
    atomicAdd(row + cxb, val * ax * ay);
    if (cxb + 1 < WIDTH) atomicAdd(row + cxb + 1, val * bx * ay);
    if (cyb + 1 < HEIGHT) {
        row += WIDTH;
        atomicAdd(row + cxb, val * ax * by);
        if (cxb + 1 < WIDTH) atomicAdd(row + cxb + 1, val * bx * by);
    }
}

extern "C" void kernel_launch(void* const* d_in, const int* in_sizes, int n_in,
                              void* d_out, int out_size, void* d_ws, size_t ws_size,
                              hipStream_t stream) {
    const float* x = (const float*)d_in[0];
    const float* y = (const float*)d_in[1];
    const float* v = (const float*)d_in[2];
    float* out = (float*)d_out;
    int n = in_sizes[0];
    int ppb = ((n + NB - 1) / NB + 7) & ~7;   // multiple of 8 -> 16B alignment

    // Workspace: payload (NB*BSTRIDE*8 = 16.8 MB) | packed off|cnt [t][b] (1 MB).
    size_t off_payload = 0;
    size_t off_runcnt  = off_payload + (size_t)NB * BSTRIDE * sizeof(uint2);
    size_t need        = off_runcnt + (size_t)NB * NTILES * sizeof(unsigned);
    bool caps_ok = (ppb <= BSTRIDE) && (out_size == IMG_ELEMS);

    if (ws_size >= need && caps_ok) {
        char* ws = (char*)d_ws;
        uint2*    payload = (uint2*)(ws + off_payload);
        unsigned* runCnt  = (unsigned*)(ws + off_runcnt);

        void* args[8] = { (void*)&x, (void*)&y, (void*)&v, (void*)&payload,
                          (void*)&runCnt, (void*)&out, (void*)&n, (void*)&ppb };
        hipError_t e = hipLaunchCooperativeKernel((const void*)k_fused,
                                                  dim3(NB), dim3(BT),
                                                  (void**)args, 0u, stream);
        if (e != hipSuccess) {
            (void)hipGetLastError();       // clear; fall back to R16 path
            k_sortlocal<<<NB, BT, 0, stream>>>(x, y, v, payload, runCnt,
                                               (float4*)out, n, ppb);
            k_accum<<<NTILES, BT, 0, stream>>>(payload, runCnt, out);
        }
    } else {
        (void)hipMemsetAsync(out, 0, (size_t)out_size * sizeof(float), stream);
        splat_direct<<<(n + 255) / 256, 256, 0, stream>>>(x, y, v, out, n);
    }
}

// Round 7
// 94.479 us; speedup vs baseline: 2.3990x; 2.3990x over previous
//
#include <hip/hip_runtime.h>
#include <hip/hip_bf16.h>

#define WIDTH 1024
#define HEIGHT 1024
#define IMG_ELEMS (WIDTH * HEIGHT)
#define TPX 32                 // tiles per axis (32x32-pixel tiles)
#define NTILES (TPX * TPX)     // 1024
#define NB 256                 // blocks in sortlocal
#define BT 1024                // threads per block
#define BSTRIDE 8192           // payload entries per block region (ppb <= 8192)
#define CAPP 36                // max points per pixel bucket      (lambda=7.63)
#define PTS_CAP 8448           // max points per tile              (lambda=7812)

// Shared-memory carve for k_accum (u32 units). pts region is reused as the
// T01/T11 exchange planes after the per-pixel reduction.
#define OFF_PTS   0
#define OFF_BIDX  (OFF_PTS + 2 * PTS_CAP)            // uint16[NTILES*CAPP]
#define OFF_HCNT  (OFF_BIDX + (NTILES * CAPP) / 2)
#define OFF_RCNT  (OFF_HCNT + NTILES)
#define OFF_RDST  (OFF_RCNT + NB)
#define OFF_ROFF  (OFF_RDST + NB)
#define OFF_STMP  (OFF_ROFF + NB)
#define SMEM_U32  (OFF_STMP + NB)                    // 37376 u32 = 149504 B

// sigma=0.1 -> 2x2 separable splat (taps beyond the bracketing pair < 2e-22).
// ax = wx0/(wx0+wx1) = 1/(1+exp(100*xf-50)).
// Measured HW model: global fp32 atomic = 32B memory-side txn (~20 G/s);
// LDS atomics ~2.9 cyc/lane on the PER-CU pipe (R15: 4 atomics/pt = 52 us
// regression; 1 atomic/pt/pass = ~9.4 us/pass floor); cooperative
// this_grid().sync() costs O(100 us) on MI355X (R17: fused kernel 146 us,
// all pipes idle -- device-scope release/acquire across 8 non-coherent XCD
// L2s + halved pass-1 occupancy; NEVER fuse via grid sync here); harness
// poison/restore ~65-70 us fixed floor; ~2 us per graph launch.
// R18: revert to the measured-best R16 two-kernel structure (94.5 us):
// transposed runCnt [t][b] + 1-LDS-atomic/pt bucket + owner-reduce +
// fused stencil. Kernel-side ~25 us vs ~19 us LDS-atomic algorithmic floor.

__device__ __forceinline__ void point_geom(float px, float py, int& cxb, int& cyb,
                                           float& ax, float& ay) {
    // (p - X0)/DX == (p + 1) * 512 exactly (DX = 2^-9).
    float xp = (px + 1.0f) * 512.0f;
    float yp = (py + 1.0f) * 512.0f;
    int xb = (int)floorf(xp);
    int yb = (int)floorf(yp);
    float xf = xp - (float)xb;
    float yf = yp - (float)yb;
    // wx1/wx0 = exp(100*xf - 50)  ->  ax = 1/(1 + exp(100*xf - 50)).
    ax = 1.0f / (1.0f + __expf(100.0f * xf - 50.0f));
    ay = 1.0f / (1.0f + __expf(100.0f * yf - 50.0f));
    cxb = min(max(xb, 0), WIDTH - 1);
    cyb = min(max(yb, 0), HEIGHT - 1);
}

// Pass 1 (fused zero+count+sort+pack): zeros this block's slice of out, one
// LDS cursor atomic per point (tile count + rank), exclusive scan over the
// 1024 tile counts, scatter payloads into a dense 64 KB LDS staging buffer,
// then stream the block's region out coalesced. Emits packed off<<16|cnt
// in TRANSPOSED layout runCnt[t*NB + b] (coalesced pass-2 read).
__global__ void __launch_bounds__(BT)
k_sortlocal(const float* __restrict__ x, const float* __restrict__ y,
            const float* __restrict__ v, uint2* __restrict__ payload,
            unsigned* __restrict__ runCnt, float4* __restrict__ outv,
            int n, int ppb) {
    __shared__ unsigned cursor[NTILES];
    __shared__ unsigned wtot[BT / 64];
    __shared__ __align__(16) uint2 stage[BSTRIDE];   // 64 KB dense staging

    int b = blockIdx.x;
    int p = threadIdx.x;
    cursor[p] = 0u;
    // Zero out: 262144 float4 total / 256 blocks = 1024 float4 per block.
    outv[(unsigned)b * 1024u + p] = make_float4(0.f, 0.f, 0.f, 0.f);
    __syncthreads();

    int lo = b * ppb;                       // ppb % 8 == 0 -> 16B-aligned base
    int hi = min(n, lo + ppb);

    // Each thread holds <= 8 points in registers across the scan.
    uint2 pay[8];
    unsigned meta[8];                       // tile<<16 | pos ; ~0u = invalid

    auto enc = [&](int s, float px, float py, float pv) {
        int cxb, cyb; float ax, ay;
        point_geom(px, py, cxb, cyb, ax, ay);
        unsigned tile = (unsigned)((cyb >> 5) * TPX + (cxb >> 5));
        unsigned pos = atomicAdd(&cursor[tile], 1u);     // pos < ppb <= 8192
        unsigned axq = (unsigned)(ax * 2047.0f + 0.5f);
        unsigned ayq = (unsigned)(ay * 2047.0f + 0.5f);
        pay[s] = make_uint2(__float_as_uint(pv),
                            axq | (ayq << 11) | ((unsigned)(cxb & 31) << 22) |
                            ((unsigned)(cyb & 31) << 27));
        meta[s] = (tile << 16) | pos;
    };

#pragma unroll
    for (int it = 0; it < 2; ++it) {        // BT*4*2 = 8192 >= ppb
        int base = lo + p * 4 + it * (BT * 4);
        if (base + 3 < hi) {
            float4 x4 = *(const float4*)&x[base];
            float4 y4 = *(const float4*)&y[base];
            float4 v4 = *(const float4*)&v[base];
            enc(it * 4 + 0, x4.x, y4.x, v4.x);
            enc(it * 4 + 1, x4.y, y4.y, v4.y);
            enc(it * 4 + 2, x4.z, y4.z, v4.z);
            enc(it * 4 + 3, x4.w, y4.w, v4.w);
        } else {
#pragma unroll
            for (int j = 0; j < 4; ++j) {
                int idx = base + j;
                if (idx < hi) enc(it * 4 + j, x[idx], y[idx], v[idx]);
                else          meta[it * 4 + j] = 0xFFFFFFFFu;
            }
        }
    }
    __syncthreads();

    // Exclusive scan of the 1024 tile counts (shuffle + 16 wave partials).
    unsigned c = cursor[p];
    unsigned lane = p & 63, w = p >> 6;
    unsigned vsc = c;
#pragma unroll
    for (int d = 1; d < 64; d <<= 1) {
        unsigned t_ = __shfl_up(vsc, d, 64);
        if (lane >= (unsigned)d) vsc += t_;
    }
    if (lane == 63) wtot[w] = vsc;
    __syncthreads();
    if (p == 0) {
        unsigned a = 0;
#pragma unroll
        for (int k = 0; k < BT / 64; ++k) { unsigned t_ = wtot[k]; wtot[k] = a; a += t_; }
    }
    __syncthreads();
    unsigned excl = vsc - c + wtot[w];      // excl <= 8192, c <= 8192
    runCnt[(unsigned)p * NB + (unsigned)b] = (excl << 16) | c;   // transposed
    cursor[p] = excl;
    __syncthreads();

    // Scatter into the dense LDS staging buffer (random 8B LDS writes).
#pragma unroll
    for (int s = 0; s < 8; ++s) {
        unsigned m = meta[s];
        if (m != 0xFFFFFFFFu)
            stage[cursor[m >> 16] + (m & 0xFFFFu)] = pay[s];
    }
    __syncthreads();

    // Stream out coalesced: block region = payload[b*8192 .. b*8192+ppb).
    int nv = ppb >> 1;                      // uint4 = 2 entries; ppb % 8 == 0
    uint4* dstv = (uint4*)(payload + ((size_t)b << 13));
    const uint4* srcv = (const uint4*)stage;
    for (int i = p; i < nv; i += BT) dstv[i] = srcv[i];
}

// Pass 2: one block per tile (static swizzle: heavy tiles [16,31]^2 first).
// Gather the tile's 256 runs into LDS (8 runs per wave in parallel), bucket
// by pixel (one LDS atomic/pt), reduce each pixel in registers into 4
// separable tap sums, then fuse the 4-pt stencil: interior via LDS/shuffle
// exchange + plain store, tile borders + cross-tile halo via global atomics
// (out pre-zeroed by k_sortlocal).
__global__ void __launch_bounds__(BT)
k_accum(const uint2* __restrict__ payload, const unsigned* __restrict__ runCnt,
        float* __restrict__ out) {
    __shared__ unsigned smem[SMEM_U32];
    uint2*          pts  = (uint2*)&smem[OFF_PTS];
    unsigned short* bidx = (unsigned short*)&smem[OFF_BIDX];
    unsigned*       hcnt = &smem[OFF_HCNT];
    unsigned*       rcnt = &smem[OFF_RCNT];
    unsigned*       rdst = &smem[OFF_RDST];
    unsigned*       roff = &smem[OFF_ROFF];
    unsigned*       stmp = &smem[OFF_STMP];
    float*          exT01 = (float*)&smem[OFF_PTS];        // alias (after reduce)
    float*          exT11 = (float*)&smem[OFF_PTS + BT];

    unsigned b = blockIdx.x;
    // Static swizzle: blocks 0..255 -> tiles [16,31]x[16,31]; rest -> complement.
    unsigned t;
    if (b < 256u) {
        t = (16u + (b >> 4)) * 32u + 16u + (b & 15u);
    } else {
        unsigned r = b - 256u;
        if (r < 512u) t = r;                                   // ty 0..15
        else { unsigned q = r - 512u; t = (16u + (q >> 4)) * 32u + (q & 15u); }
    }

    int p = threadIdx.x;
    unsigned lane = p & 63, w = p >> 6;
    unsigned c0 = 0u;
    if (p < NB) {
        unsigned pk = runCnt[t * NB + (unsigned)p];   // coalesced (transposed)
        c0 = pk & 0xFFFFu;
        rcnt[p] = c0;
        roff[p] = pk >> 16;
    }
    hcnt[p] = 0u;
    // Quick total (wave reduce over the 4 runCnt-holding waves).
    unsigned tsum = c0;
#pragma unroll
    for (int d = 32; d >= 1; d >>= 1) tsum += __shfl_down(tsum, d, 64);
    if (p < NB && lane == 0) rdst[w] = tsum;
    __syncthreads();
    unsigned total = rdst[0] + rdst[1] + rdst[2] + rdst[3];
    if (total == 0) return;      // out pre-zeroed; halo from neighbors is atomic

    // Exclusive scan of the 256 run counts (shuffle + 4 partials).
    unsigned vsc = c0;
#pragma unroll
    for (int d = 1; d < 64; d <<= 1) {
        unsigned tmp = __shfl_up(vsc, d, 64);
        if (lane >= (unsigned)d) vsc += tmp;
    }
    __syncthreads();             // rdst partials consumed by all threads above
    if (p < NB && lane == 63) stmp[w] = vsc;
    __syncthreads();
    if (p == 0) {
        unsigned a = 0;
#pragma unroll
        for (int k = 0; k < 4; ++k) { unsigned tt = stmp[k]; stmp[k] = a; a += tt; }
    }
    __syncthreads();
    if (p < NB) rdst[p] = vsc - c0 + stmp[w];
    __syncthreads();

    // Gather + bucket: wave w handles runs [w*16, w*16+16), 8 in parallel
    // (8 lanes per run) -> 8x fewer serial VMEM issues than one-run-at-a-time.
    unsigned sub = lane >> 3, jl = lane & 7u;
#pragma unroll
    for (int kk = 0; kk < 2; ++kk) {
        int r = (int)w * 16 + kk * 8 + (int)sub;
        unsigned cnt = rcnt[r], dst = rdst[r];
        const unsigned long long* g =
            (const unsigned long long*)(payload + (((size_t)r) << 13) + roff[r]);
        for (unsigned j = jl; j < cnt; j += 8) {
            unsigned long long raw = __builtin_nontemporal_load(&g[j]);
            uint2 pl = make_uint2((unsigned)raw, (unsigned)(raw >> 32));
            unsigned slot = dst + j;
            if (slot < PTS_CAP) {
                pts[slot] = pl;
                unsigned pix = (pl.y >> 22) & 1023u;
                unsigned pos = atomicAdd(&hcnt[pix], 1u);
                if (pos < CAPP) bidx[pix * CAPP + pos] = (unsigned short)slot;
            }
        }
    }
    __syncthreads();

    // Per-pixel register reduction (conflict-free ownership).
    float t00 = 0.0f, t10 = 0.0f, t01 = 0.0f, t11 = 0.0f;
    unsigned cnt = min(hcnt[p], (unsigned)CAPP);
    for (unsigned e = 0; e < cnt; ++e) {
        uint2 sp = pts[bidx[p * CAPP + e]];
        float val = __uint_as_float(sp.x);
        float ax = (float)(sp.y & 2047u) * (1.0f / 2047.0f);
        float ay = (float)((sp.y >> 11) & 2047u) * (1.0f / 2047.0f);
        float bx = 1.0f - ax, by = 1.0f - ay;
        t00 += val * ax * ay;
        t10 += val * bx * ay;
        t01 += val * ax * by;
        t11 += val * bx * by;
    }
    __syncthreads();             // pts/bidx dead; reuse as exchange planes
    exT01[p] = t01;
    exT11[p] = t11;
    __syncthreads();

    int lx = p & 31, ly = p >> 5;
    int gx = (int)((t & 31u) << 5) + lx;
    int gy = (int)((t >> 5) << 5) + ly;
    size_t g = (size_t)gy * WIDTH + gx;
    float t10l = __shfl_up(t10, 1, 64);    // T10 of (ly, lx-1): same wave (2 rows/wave)
    float sum = t00;
    if (lx > 0) sum += t10l;
    if (ly > 0) sum += exT01[p - 32];
    if (lx > 0 && ly > 0) sum += exT11[p - 33];
    if (lx == 0 || ly == 0) atomicAdd(&out[g], sum);   // may race with neighbor halo
    else out[g] = sum;                                  // interior: exclusive

    // Cross-tile halo exports (targets are col0/row0 pixels of neighbors,
    // which are always written atomically).
    bool xr = (gx + 1 < WIDTH), yd = (gy + 1 < HEIGHT);
    if (lx == 31 && xr) {
        atomicAdd(&out[g + 1], t10);
        if (yd) atomicAdd(&out[g + WIDTH + 1], t11);
    }
    if (ly == 31 && yd) {
        atomicAdd(&out[g + WIDTH], t01);
        if (lx < 31 && xr) atomicAdd(&out[g + WIDTH + 1], t11);
    }
}

// Fallback: direct memory-side atomics if workspace too small.
__global__ void __launch_bounds__(256)
splat_direct(const float* __restrict__ x, const float* __restrict__ y,
             const float* __restrict__ v, float* __restrict__ out, int n) {
    int i = blockIdx.x * blockDim.x + threadIdx.x;
    if (i >= n) return;
    int cxb, cyb; float ax, ay;
    point_geom(x[i], y[i], cxb, cyb, ax, ay);
    float val = v[i];
    float bx = 1.0f - ax, by = 1.0f - ay;
    float* row = out + cyb * WIDTH;
    atomicAdd(row + cxb, val * ax * ay);
    if (cxb + 1 < WIDTH) atomicAdd(row + cxb + 1, val * bx * ay);
    if (cyb + 1 < HEIGHT) {
        row += WIDTH;
        atomicAdd(row + cxb, val * ax * by);
        if (cxb + 1 < WIDTH) atomicAdd(row + cxb + 1, val * bx * by);
    }
}

extern "C" void kernel_launch(void* const* d_in, const int* in_sizes, int n_in,
                              void* d_out, int out_size, void* d_ws, size_t ws_size,
                              hipStream_t stream) {
    const float* x = (const float*)d_in[0];
    const float* y = (const float*)d_in[1];
    const float* v = (const float*)d_in[2];
    float* out = (float*)d_out;
    int n = in_sizes[0];
    // ppb multiple of 8 so every block's float4 base stays 16B-aligned.
    int ppb = ((n + NB - 1) / NB + 7) & ~7;

    // Workspace: payload (NB*BSTRIDE*8 = 16.8 MB) | packed off|cnt [t][b] (1 MB).
    size_t off_payload = 0;
    size_t off_runcnt  = off_payload + (size_t)NB * BSTRIDE * sizeof(uint2);
    size_t need        = off_runcnt + (size_t)NB * NTILES * sizeof(unsigned);
    bool caps_ok = (ppb <= BSTRIDE) && (out_size == IMG_ELEMS);

    if (ws_size >= need && caps_ok) {
        char* ws = (char*)d_ws;
        uint2*    payload = (uint2*)(ws + off_payload);
        unsigned* runCnt  = (unsigned*)(ws + off_runcnt);

        k_sortlocal<<<NB, BT, 0, stream>>>(x, y, v, payload, runCnt,
                                           (float4*)out, n, ppb);
        k_accum<<<NTILES, BT, 0, stream>>>(payload, runCnt, out);
    } else {
        (void)hipMemsetAsync(out, 0, (size_t)out_size * sizeof(float), stream);
        splat_direct<<<(n + 255) / 256, 256, 0, stream>>>(x, y, v, out, n);
    }
}